// Round 10
// baseline (182.148 us; speedup 1.0000x reference)
//
#include <hip/hip_runtime.h>

typedef float f32x4 __attribute__((ext_vector_type(4)));
typedef short bf16x8 __attribute__((ext_vector_type(8)));
typedef _Float16 f16x8 __attribute__((ext_vector_type(8)));
typedef unsigned short u16;

__device__ __forceinline__ u16 f2bf(float f) {
  unsigned int u = __float_as_uint(f);
  u = u + 0x7fffu + ((u >> 16) & 1u);  // RNE
  return (u16)(u >> 16);
}
__device__ __forceinline__ float bf2f(u16 h) {
  return __uint_as_float(((unsigned int)h) << 16);
}
__device__ __forceinline__ u16 f2h(float f) {
  _Float16 h = (_Float16)f;  // v_cvt_f16_f32, RNE
  union { _Float16 h; u16 u; } cv;
  cv.h = h;
  return cv.u;
}

typedef unsigned int as1_uint __attribute__((address_space(1)));
typedef unsigned int as3_uint __attribute__((address_space(3)));
// async global->LDS, 16B/lane; LDS dest = wave-uniform base + lane*16
__device__ __forceinline__ void gl_lds16(const void* g, void* l) {
  __builtin_amdgcn_global_load_lds((as1_uint*)g, (as3_uint*)l, 16, 0, 0);
}

// Image unit = 8KB: [128 rows][32 k] elems, chunk swizzle c' = c ^ ((r>>1)&3).
// Frag read offset in image: r*32 + ((quad ^ ((lm>>1)&3))*8) — 0-conflict.

// ============ fused prep: conv_x + conv_w(Wqkv) + conv_w(Wo) + sums=0 ======
// One dispatch replaces 3 kernels + 1 memset (verified R9: −5.2 µs).
__device__ __forceinline__ void conv_w_body(const float* __restrict__ src,
                                            int ncols, u16* __restrict__ dst,
                                            int slab, int kg,
                                            float (*tl)[132]) {
  const int t = threadIdx.x;
  const int n0 = slab * 128, k0 = kg * 64;
#pragma unroll
  for (int i = 0; i < 8; i++) {
    const int fidx = i * 256 + t;
    const int r = fidx >> 5, c4 = (fidx & 31) * 4;
    *(float4*)&tl[r][c4] = *(const float4*)&src[(size_t)(k0 + r) * ncols + n0 + c4];
  }
  __syncthreads();
  const size_t base = (size_t)slab * 131072 + (size_t)(kg * 2) * 4096;
#pragma unroll
  for (int i = 0; i < 4; i++) {
    const int g = i * 256 + t;
    const int img = g >> 9, ci = g & 511;
    const int r = ci >> 2, cp = ci & 3;
    const int c = cp ^ ((r >> 1) & 3);
    const int klc = img * 32 + c * 8;
    ushort4 h0, h1;
    float v[8];
#pragma unroll
    for (int e = 0; e < 8; e++) v[e] = tl[klc + e][r];
    h0.x = f2h(v[0]); h0.y = f2h(v[1]); h0.z = f2h(v[2]); h0.w = f2h(v[3]);
    h1.x = f2h(v[4]); h1.y = f2h(v[5]); h1.z = f2h(v[6]); h1.w = f2h(v[7]);
    *(ushort4*)&dst[base + g * 8] = h0;
    *(ushort4*)&dst[base + g * 8 + 4] = h1;
  }
}

__global__ __launch_bounds__(256) void prep_kernel(
    const float* __restrict__ x, const float* __restrict__ Wqkv,
    const float* __restrict__ Wo, u16* __restrict__ Xp, u16* __restrict__ Wp,
    u16* __restrict__ Wop, float* __restrict__ sums) {
  __shared__ float tl[64][132];
  const int L = blockIdx.x;
  if (L == 0 && threadIdx.x < 2) sums[threadIdx.x] = 0.f;
  if (L < 2048) {
    // conv_x: x f32 -> X' f16 images (32 slabs x 32 ksteps)
    const int g = L * 256 + threadIdx.x;
    const int o = g * 8;
    const int slab = o >> 17;
    const int rem = o & 131071;
    const int kstep = rem >> 12;
    const int rem2 = rem & 4095;
    const int r = rem2 >> 5;
    const int cp = (rem2 & 31) >> 3;
    const int c = cp ^ ((r >> 1) & 3);
    const int s = slab * 128 + r;
    const int k = kstep * 32 + c * 8;
    const float4 v0 = *(const float4*)&x[(size_t)s * 1024 + k];
    const float4 v1 = *(const float4*)&x[(size_t)s * 1024 + k + 4];
    ushort4 a, b;
    a.x = f2h(v0.x); a.y = f2h(v0.y); a.z = f2h(v0.z); a.w = f2h(v0.w);
    b.x = f2h(v1.x); b.y = f2h(v1.y); b.z = f2h(v1.z); b.w = f2h(v1.w);
    *(ushort4*)&Xp[o] = a;
    *(ushort4*)&Xp[o + 4] = b;
  } else if (L < 2432) {
    const int idx = L - 2048;  // 24 slabs x 16 kg
    conv_w_body(Wqkv, 3072, Wp, idx % 24, idx / 24, tl);
  } else {
    const int idx = L - 2432;  // 8 slabs x 16 kg
    conv_w_body(Wo, 1024, Wop, idx % 8, idx / 8, tl);
  }
}

// ======= fused qkv GEMM — 256x256 tile, 8 waves, BK=64, m201 phase order ===
// At structural ceiling: 594 TF at 75% grid fill = 792 TF/active-CU ≈ m248's
// 848 TF reference for 256²/8ph/K=1024. Frozen (verified R6).
__global__ __launch_bounds__(512, 2) void gemm_qkv_kernel(
    const u16* __restrict__ Xp, const u16* __restrict__ Wp,
    u16* __restrict__ qf, u16* __restrict__ kf, u16* __restrict__ vT,
    const float* __restrict__ scale_q, const float* __restrict__ scale_k,
    float* __restrict__ sums) {
  __shared__ u16 SA[2][4][4096];  // X-data: [buf][k2*2+slab][8KB image]
  __shared__ u16 SB[2][4][4096];  // W-data
  const int tid = threadIdx.x, wv = tid >> 6, lane = tid & 63;
  const int lm = lane & 15, quad = lane >> 4;
  const int wvM = wv >> 2, wvN = wv & 3;  // wave grid 2(M) x 4(N)
  // bijective XCD decode: 192 blocks = 8 xcd x 24; each xcd: 4 bm x 6 bn
  const int L = blockIdx.x;
  const int xcd = L & 7, idx = L >> 3;        // idx in [0,24)
  const int bmT = (xcd & 3) * 4 + (idx & 3);  // [0,16)
  const int bnT = (xcd >> 2) * 6 + (idx >> 2);// [0,12)
  const bool is_v = (bnT >= 8);
  const int fq = (quad ^ ((lm >> 1) & 3)) * 8;
  const int aOff = lm * 32 + fq;
  const u16* Xg = Xp + (size_t)bmT * 262144;  // 2 slabs of 128 rows
  const u16* Wg = Wp + (size_t)bnT * 262144;
  // B-frag sub/row bases for the 4 n-frags (B-row = wvN*64 + n*16 + lm)
  int bSub[4];
#pragma unroll
  for (int n = 0; n < 4; n++) {
    const int wn = wvN * 64 + n * 16;
    bSub[n] = ((wn >> 7) * 4096) + (wn & 127) * 32;
  }
  const u16* Ard = is_v ? &SA[0][0][0] : &SB[0][0][0];
  const u16* Brd = is_v ? &SB[0][0][0] : &SA[0][0][0];

  const f32x4 z4 = {0.f, 0.f, 0.f, 0.f};
  f32x4 acc[8][4];
#pragma unroll
  for (int i = 0; i < 8; i++)
#pragma unroll
    for (int j = 0; j < 4; j++) acc[i][j] = z4;

#define VMCNT4() asm volatile("s_waitcnt vmcnt(4)" ::: "memory")
#define VMCNT0() asm volatile("s_waitcnt vmcnt(0)" ::: "memory")
#define LGKM0() asm volatile("s_waitcnt lgkmcnt(0)" ::: "memory")
#define CFENCE() asm volatile("" ::: "memory")
#define SP1() __builtin_amdgcn_s_setprio(1)
#define SP0() __builtin_amdgcn_s_setprio(0)

  // stage one (X,W) sub-image pair (8KB each, 8 waves x 1KB) for tile tt
#define QSTAGE(tt, nb, k2, sl)                                               \
  do {                                                                       \
    const size_t go_ = (size_t)(sl)*131072 + (size_t)(2 * (tt) + (k2)) * 4096\
                       + wv * 512 + lane * 8;                                \
    gl_lds16(Xg + go_, &SA[nb][(k2)*2 + (sl)][wv * 512]);                    \
    gl_lds16(Wg + go_, &SB[nb][(k2)*2 + (sl)][wv * 512]);                    \
  } while (0)

#define READ_A(BUF, k2, mq)                                                  \
  _Pragma("unroll")                                                          \
  for (int i = 0; i < 4; i++)                                                \
    afr[i] = *(const f16x8*)&Ard[(BUF)*16384 + ((k2)*2 + wvM) * 4096 +       \
                                 ((mq)*4 + i) * 512 + aOff];
#define READ_B(BUF, k2)                                                      \
  _Pragma("unroll")                                                          \
  for (int n = 0; n < 4; n++)                                                \
    bfr[n] = *(const f16x8*)&Brd[(BUF)*16384 + (k2)*8192 + bSub[n] + aOff];
#define MFMA16(mq)                                                           \
  _Pragma("unroll")                                                          \
  for (int i = 0; i < 4; i++)                                                \
    _Pragma("unroll")                                                        \
    for (int n = 0; n < 4; n++)                                              \
      acc[(mq)*4 + i][n] = __builtin_amdgcn_mfma_f32_16x16x32_f16(           \
          afr[i], bfr[n], acc[(mq)*4 + i][n], 0, 0, 0);

#define PH_WAIT_MFMA(mq)                                                     \
  CFENCE();                                                                  \
  __builtin_amdgcn_s_barrier();                                              \
  CFENCE();                                                                  \
  LGKM0();                                                                   \
  __builtin_amdgcn_sched_barrier(0);                                         \
  SP1();                                                                     \
  MFMA16(mq);                                                                \
  SP0()

  // compute tile t from BUF; stage tile t+1 into NBUF (if DOSTAGE)
#define KTILE(BUF, NBUF, t, DOSTAGE, GATE1, GATE3)                           \
  do {                                                                       \
    f16x8 bfr[4];                                                            \
    { /* ph0: k2=0, m-low */                                                 \
      f16x8 afr[4];                                                          \
      READ_A(BUF, 0, 0);                                                     \
      READ_B(BUF, 0);                                                        \
      if (DOSTAGE) QSTAGE((t) + 1, NBUF, 0, 0);                              \
      PH_WAIT_MFMA(0);                                                       \
    }                                                                        \
    { /* ph1: k2=0, m-high */                                                \
      f16x8 afr[4];                                                          \
      READ_A(BUF, 0, 1);                                                     \
      if (DOSTAGE) QSTAGE((t) + 1, NBUF, 0, 1);                              \
      GATE1; /* drain oldest-4 = this tile's k2=1 half, read in ph2 */       \
      PH_WAIT_MFMA(1);                                                       \
    }                                                                        \
    { /* ph2: k2=1, m-low */                                                 \
      f16x8 afr[4];                                                          \
      READ_A(BUF, 1, 0);                                                     \
      READ_B(BUF, 1);                                                        \
      if (DOSTAGE) QSTAGE((t) + 1, NBUF, 1, 0);                              \
      PH_WAIT_MFMA(0);                                                       \
    }                                                                        \
    { /* ph3: k2=1, m-high */                                                \
      f16x8 afr[4];                                                          \
      READ_A(BUF, 1, 1);                                                     \
      if (DOSTAGE) QSTAGE((t) + 1, NBUF, 1, 1);                              \
      GATE3; /* drain oldest-4 = next tile's k2=0 half, read in next ph0 */  \
      PH_WAIT_MFMA(1);                                                       \
    }                                                                        \
    /* barrier_B (tile boundary): all waves consumed BUF before any wave   */\
    /* may issue next tile's re-stage into BUF.                            */\
    CFENCE();                                                                \
    __builtin_amdgcn_s_barrier();                                            \
    CFENCE();                                                                \
  } while (0)

  // prologue: stage tile 0 into buf0, k-major order; gate k2=0 + barrier
  QSTAGE(0, 0, 0, 0);
  QSTAGE(0, 0, 0, 1);
  QSTAGE(0, 0, 1, 0);
  QSTAGE(0, 0, 1, 1);
  VMCNT4();
  __builtin_amdgcn_s_barrier();
  CFENCE();
#pragma unroll 1
  for (int t = 0; t < 14; t += 2) {
    KTILE(0, 1, t, true, VMCNT4(), VMCNT4());
    KTILE(1, 0, t + 1, true, VMCNT4(), VMCNT4());
  }
  KTILE(0, 1, 14, true, VMCNT4(), VMCNT4());
  KTILE(1, 0, 15, false, VMCNT0(), (void)0);
#undef KTILE
#undef PH_WAIT_MFMA
#undef READ_A
#undef READ_B
#undef MFMA16
#undef QSTAGE

  const int bn = bnT * 256, bm = bmT * 256;
  if (!is_v) {
    // swapped: acc[mi][ni][i] = C[col=bn+wvM*128+mi*16+quad*4+i][s=...]
    const bool is_k = (bnT >= 4);
    u16* dst = is_k ? kf : qf;
    float ss = 0.f;
#pragma unroll
    for (int mi = 0; mi < 8; mi++) {
      const int col0 = bn + wvM * 128 + mi * 16 + quad * 4;
      const int hh = (col0 >> 6) & 15, d0 = col0 & 63;
      const int dhi = d0 >> 5, cc = (d0 & 31) >> 3, eo = d0 & 7;
      float sc[4] = {1.f, 1.f, 1.f, 1.f};
      if (is_k) {
        const float4 sq = *(const float4*)&scale_q[d0];
        const float4 sk = *(const float4*)&scale_k[d0];
        sc[0] = sq.x * sk.x; sc[1] = sq.y * sk.y;
        sc[2] = sq.z * sk.z; sc[3] = sq.w * sk.w;
      }
#pragma unroll
      for (int ni = 0; ni < 4; ni++) {
        const int s = bm + wvN * 64 + ni * 16 + lm;
        const int b = s >> 10, sl = s & 1023, st = sl >> 6, r = sl & 63;
        const size_t off = ((size_t)((b * 16 + hh) * 16 + st)) * 4096 +
                           dhi * 2048 + r * 32 + ((cc ^ ((r >> 1) & 3)) * 8) + eo;
        ushort4 h4;
#pragma unroll
        for (int i = 0; i < 4; i++) {
          const float a = acc[mi][ni][i];
          ss += a * a;  // raw (pre-scale) for global RMS
          const u16 hv = f2h(a * sc[i]);
          if (i == 0) h4.x = hv;
          else if (i == 1) h4.y = hv;
          else if (i == 2) h4.z = hv;
          else h4.w = hv;
        }
        *(ushort4*)&dst[off] = h4;
      }
    }
#pragma unroll
    for (int m = 32; m >= 1; m >>= 1) ss += __shfl_xor(ss, m, 64);
    if (lane == 0) atomicAdd(&sums[is_k ? 1 : 0], ss);
  } else {
    // normal: acc[mi][ni][i] = C[s=bm+wvM*128+mi*16+quad*4+i][d-col]; bf16
#pragma unroll
    for (int ni = 0; ni < 4; ni++) {
      const int col = (bn - 2048) + wvN * 64 + ni * 16 + lm;
      const int d = col & 63, hh = col >> 6;
#pragma unroll
      for (int mi = 0; mi < 8; mi++) {
        const int s0 = bm + wvM * 128 + mi * 16 + quad * 4;
        const int b = s0 >> 10, sl = s0 & 1023, st = sl >> 6;
        const int sh = (sl & 63) >> 5, cc = (sl & 31) >> 3, eo = sl & 7;
        const size_t off = ((size_t)((b * 16 + hh) * 16 + st)) * 4096 +
                           sh * 2048 + d * 32 + ((cc ^ ((d >> 1) & 3)) * 8) + eo;
        ushort4 v4;
        v4.x = f2bf(acc[mi][ni][0]);
        v4.y = f2bf(acc[mi][ni][1]);
        v4.z = f2bf(acc[mi][ni][2]);
        v4.w = f2bf(acc[mi][ni][3]);
        *(ushort4*)&vT[off] = v4;
      }
    }
  }
#undef VMCNT4
#undef VMCNT0
#undef LGKM0
#undef CFENCE
#undef SP1
#undef SP0
}

// ============ fused attention — f16 QK (swapped), bf16 PV ============
// R6-verified structure + two micro-opts this round:
// (1) T5 setprio(1) wrapped around MFMA clusters only (m191: attn +4-7%;
//     waves here diverge between barrier pairs -> scheduler has roles to
//     arbitrate). exp/pack stay at prio 0.
// (2) softmax exp folded: exp(c*cs-60) = exp2(fma(c, cs*log2e, -60*log2e))
//     -> 1 FMA + 1 v_exp instead of mul/sub/(mul)/exp.
__global__ __launch_bounds__(256) void attn_kernel(
    const u16* __restrict__ qf, const u16* __restrict__ kf,
    const u16* __restrict__ vT, const float* __restrict__ sums,
    u16* __restrict__ z) {
  __shared__ u16 Ks0[4096], Vs0[4096], Ks1[4096], Vs1[4096];  // 32 KB
  __shared__ u16 pb[4][2][16][64];                            // 16 KB
  const int tid = threadIdx.x, wv = tid >> 6, lane = tid & 63;
  const int lm = lane & 15, quad = lane >> 4;
  const int fq = (quad ^ ((lm >> 1) & 3)) * 8;
  const int L = blockIdx.x;
  const int xcd = L & 7, idx = L >> 3;   // idx in [0,64)
  const int qt8 = idx & 7, p = idx >> 3; // p in [0,8)
  const int pair = xcd * 8 + p;          // [0,64)
  const int hh = pair & 15, b = pair >> 4;
  const float inv_rq = 1.f / (sqrtf(sums[0] * (1.f / 4194304.f)) + 1e-6f);
  const float inv_rk = 1.f / (sqrtf(sums[1] * (1.f / 4194304.f)) + 1e-6f);
  const float cs = inv_rq * inv_rk;
  const float csl = cs * 1.44269504f;   // cs * log2(e)
  const float eoff = -86.5617025f;      // -60 * log2(e)
  const size_t hb = ((size_t)(b * 16 + hh)) * 65536;
  const u16* Kg = kf + hb;
  const u16* Vg = vT + hb;
  const int dof = wv * 1024;

  // q frags (B-operand role): B[n=lm][k=d], rows = wave's q set
  f16x8 aF[2][2];
#pragma unroll
  for (int qs = 0; qs < 2; qs++) {
    const int soff = wv * 32 + qs * 16;
    const size_t qb = hb + (size_t)(qt8 * 2 + (soff >> 6)) * 4096 +
                      (size_t)((soff & 63) + lm) * 32 + fq;
    aF[qs][0] = *(const f16x8*)&qf[qb];
    aF[qs][1] = *(const f16x8*)&qf[qb + 2048];
  }
  const f32x4 zz = {0.f, 0.f, 0.f, 0.f};
  f32x4 zac[2][4];
#pragma unroll
  for (int qs = 0; qs < 2; qs++)
#pragma unroll
    for (int dt = 0; dt < 4; dt++) zac[qs][dt] = zz;
  float rs[2] = {0.f, 0.f};

#define AISSUE(it, Ks, Vs)                                    \
  do {                                                        \
    const size_t tb_ = (size_t)(it) * 4096;                   \
    gl_lds16(Kg + tb_ + dof + lane * 8, &Ks[dof]);            \
    gl_lds16(Kg + tb_ + dof + 512 + lane * 8, &Ks[dof + 512]);\
    gl_lds16(Vg + tb_ + dof + lane * 8, &Vs[dof]);            \
    gl_lds16(Vg + tb_ + dof + 512 + lane * 8, &Vs[dof + 512]);\
  } while (0)

#define ATTN_BODY(it, Ks, Vs, Kn, Vn, do_issue)                               \
  do {                                                                        \
    /* pre-read all frags of this tile */                                     \
    f16x8 kf0[4], kf1[4];                                                     \
    bf16x8 bv[2][4];                                                          \
_Pragma("unroll")                                                             \
    for (int nt = 0; nt < 4; nt++) {                                          \
      const int ro = (nt * 16 + lm) * 32 + fq;                                \
      kf0[nt] = *(const f16x8*)&Ks[ro];                                       \
      kf1[nt] = *(const f16x8*)&Ks[2048 + ro];                                \
    }                                                                         \
_Pragma("unroll")                                                             \
    for (int ch = 0; ch < 2; ch++)                                            \
_Pragma("unroll")                                                             \
      for (int dt = 0; dt < 4; dt++)                                          \
        bv[ch][dt] = *(const bf16x8*)&Vs[ch * 2048 + (dt * 16 + lm) * 32 + fq];\
    if (do_issue) AISSUE((it) + 1, Kn, Vn);                                   \
    /* QK swapped + softmax numerator + p to LDS (b64, swizzled) */           \
_Pragma("unroll")                                                             \
    for (int qs = 0; qs < 2; qs++) {                                          \
_Pragma("unroll")                                                             \
      for (int nt = 0; nt < 4; nt++) {                                        \
        f32x4 c = zz;                                                         \
        __builtin_amdgcn_s_setprio(1);                                        \
        c = __builtin_amdgcn_mfma_f32_16x16x32_f16(kf0[nt], aF[qs][0], c, 0, 0, 0);\
        c = __builtin_amdgcn_mfma_f32_16x16x32_f16(kf1[nt], aF[qs][1], c, 0, 0, 0);\
        __builtin_amdgcn_s_setprio(0);                                        \
        const int k4 = nt * 4 + quad;                                         \
        const int sw = (k4 & 8) | ((k4 ^ lm) & 7);                            \
        ushort4 pw;                                                           \
        float p0 = exp2f(fmaf(c[0], csl, eoff));                              \
        float p1 = exp2f(fmaf(c[1], csl, eoff));                              \
        float p2 = exp2f(fmaf(c[2], csl, eoff));                              \
        float p3 = exp2f(fmaf(c[3], csl, eoff));                              \
        rs[qs] += (p0 + p1) + (p2 + p3);                                      \
        pw.x = f2bf(p0); pw.y = f2bf(p1); pw.z = f2bf(p2); pw.w = f2bf(p3);   \
        *(ushort4*)&pb[wv][qs][lm][sw * 4] = pw;                              \
      }                                                                       \
    }                                                                         \
    /* PV swapped: A=v rows=d, B=p rows=q (b64 pair reads, swizzled) */       \
_Pragma("unroll")                                                             \
    for (int ch = 0; ch < 2; ch++) {                                          \
_Pragma("unroll")                                                             \
      for (int qs = 0; qs < 2; qs++) {                                        \
        const int k4a = ch * 8 + quad * 2, k4b = k4a + 1;                     \
        const ushort4 lo4 =                                                   \
            *(const ushort4*)&pb[wv][qs][lm][((k4a & 8) | ((k4a ^ lm) & 7)) * 4];\
        const ushort4 hi4 =                                                   \
            *(const ushort4*)&pb[wv][qs][lm][((k4b & 8) | ((k4b ^ lm) & 7)) * 4];\
        bf16x8 ap;                                                            \
        ap[0] = (short)lo4.x; ap[1] = (short)lo4.y;                           \
        ap[2] = (short)lo4.z; ap[3] = (short)lo4.w;                           \
        ap[4] = (short)hi4.x; ap[5] = (short)hi4.y;                           \
        ap[6] = (short)hi4.z; ap[7] = (short)hi4.w;                           \
        __builtin_amdgcn_s_setprio(1);                                        \
_Pragma("unroll")                                                             \
        for (int dt = 0; dt < 4; dt++)                                        \
          zac[qs][dt] = __builtin_amdgcn_mfma_f32_16x16x32_bf16(              \
              bv[ch][dt], ap, zac[qs][dt], 0, 0, 0);                          \
        __builtin_amdgcn_s_setprio(0);                                        \
      }                                                                       \
    }                                                                         \
  } while (0)

  AISSUE(0, Ks0, Vs0);
  for (int it = 0; it < 16; it += 2) {
    __syncthreads();
    ATTN_BODY(it, Ks0, Vs0, Ks1, Vs1, true);
    __syncthreads();
    ATTN_BODY(it + 1, Ks1, Vs1, Ks0, Vs0, (it + 2 < 16));
  }
#undef AISSUE
#undef ATTN_BODY

  // rowsum for q=lm: reduce over quad groups only
#pragma unroll
  for (int qs = 0; qs < 2; qs++) {
    rs[qs] += __shfl_xor(rs[qs], 16, 64);
    rs[qs] += __shfl_xor(rs[qs], 32, 64);
  }
  const int slab = b * 8 + qt8;
#pragma unroll
  for (int qs = 0; qs < 2; qs++) {
    const float inv = 1.f / rs[qs];
    const int r = wv * 32 + qs * 16 + lm;
#pragma unroll
    for (int dt = 0; dt < 4; dt++) {
      const int kstep = hh * 2 + (dt >> 1);
      const int d0 = dt * 16 + quad * 4;
      const int cc = (d0 & 31) >> 3, eo = d0 & 7;
      const size_t off = ((size_t)(slab * 32 + kstep)) * 4096 + r * 32 +
                         ((cc ^ ((r >> 1) & 3)) * 8) + eo;
      ushort4 o;
      o.x = f2h(zac[qs][dt][0] * inv);
      o.y = f2h(zac[qs][dt][1] * inv);
      o.z = f2h(zac[qs][dt][2] * inv);
      o.w = f2h(zac[qs][dt][3] * inv);
      *(ushort4*)&z[off] = o;
    }
  }
}

// ============ output projection — f16, async-LDS dbuf, swapped =============
// XCD swizzle: flat grid 256; xcd owns 8 zp-slabs x 4 Wo-slabs -> 3MB L2 set.
__global__ __launch_bounds__(256) void gemm_o_kernel(const u16* __restrict__ Wop,
                                                     const u16* __restrict__ zp,
                                                     float* __restrict__ out) {
  __shared__ u16 As0[4096], Bs0[4096], As1[4096], Bs1[4096];
  const int tid = threadIdx.x, wv = tid >> 6, lane = tid & 63;
  const int lm = lane & 15, quad = lane >> 4;
  const int wr = (wv >> 1) * 64, wc = (wv & 1) * 64;
  const int fq = (quad ^ ((lm >> 1) & 3)) * 8;
  const int L = blockIdx.x;
  const int xcd = L & 7, idx = L >> 3;      // idx in [0,32)
  const int rr = idx & 7, cc8 = idx >> 3;   // 8 zp x 4 Wo
  const int zpS = (xcd & 3) * 8 + rr;       // [0,32)
  const int woS = (xcd >> 2) * 4 + cc8;     // [0,8)
  const u16* Ag = Wop + (size_t)woS * 131072;
  const u16* Bg = zp + (size_t)zpS * 131072;
  const int dof0 = (wv * 2) * 512, dof1 = (wv * 2 + 1) * 512;
  const f32x4 z4 = {0.f, 0.f, 0.f, 0.f};
  f32x4 acc[4][4];
#pragma unroll
  for (int i = 0; i < 4; i++)
#pragma unroll
    for (int j = 0; j < 4; j++) acc[i][j] = z4;

#define ISSUE(t, As, Bs)                                   \
  do {                                                     \
    const size_t tb_ = (size_t)(t) * 4096;                 \
    gl_lds16(Ag + tb_ + dof0 + lane * 8, &As[dof0]);       \
    gl_lds16(Ag + tb_ + dof1 + lane * 8, &As[dof1]);       \
    gl_lds16(Bg + tb_ + dof0 + lane * 8, &Bs[dof0]);       \
    gl_lds16(Bg + tb_ + dof1 + lane * 8, &Bs[dof1]);       \
  } while (0)
#define GBODY(As, Bs)                                                     \
  do {                                                                    \
    f16x8 afr[4], bfr[4];                                                 \
_Pragma("unroll")                                                         \
    for (int mi = 0; mi < 4; mi++)                                        \
      afr[mi] = *(const f16x8*)&As[(wr + mi * 16 + lm) * 32 + fq];        \
_Pragma("unroll")                                                         \
    for (int ni = 0; ni < 4; ni++)                                        \
      bfr[ni] = *(const f16x8*)&Bs[(wc + ni * 16 + lm) * 32 + fq];        \
    DO_ISSUE;                                                             \
_Pragma("unroll")                                                         \
    for (int mi = 0; mi < 4; mi++)                                        \
_Pragma("unroll")                                                         \
      for (int ni = 0; ni < 4; ni++)                                      \
        acc[mi][ni] = __builtin_amdgcn_mfma_f32_16x16x32_f16(             \
            afr[mi], bfr[ni], acc[mi][ni], 0, 0, 0);                      \
  } while (0)

  ISSUE(0, As0, Bs0);
  for (int t = 0; t < 32; t += 2) {
    __syncthreads();
#define DO_ISSUE ISSUE(t + 1, As1, Bs1)
    GBODY(As0, Bs0);
#undef DO_ISSUE
    __syncthreads();
#define DO_ISSUE if (t + 2 < 32) ISSUE(t + 2, As0, Bs0)
    GBODY(As1, Bs1);
#undef DO_ISSUE
  }
#undef ISSUE
#undef GBODY

#pragma unroll
  for (int mi = 0; mi < 4; mi++) {
    const int col0 = woS * 128 + wr + mi * 16 + quad * 4;
#pragma unroll
    for (int ni = 0; ni < 4; ni++) {
      const int s = zpS * 128 + wc + ni * 16 + lm;
      const float4 o = {acc[mi][ni][0], acc[mi][ni][1], acc[mi][ni][2],
                        acc[mi][ni][3]};
      *(float4*)&out[(size_t)s * 1024 + col0] = o;
    }
  }
}

extern "C" void kernel_launch(void* const* d_in, const int* in_sizes, int n_in,
                              void* d_out, int out_size, void* d_ws,
                              size_t ws_size, hipStream_t stream) {
  (void)in_sizes; (void)n_in; (void)out_size; (void)ws_size;
  const float* x = (const float*)d_in[0];
  const float* Wqkv = (const float*)d_in[1];
  const float* Wo = (const float*)d_in[2];
  const float* scale_q = (const float*)d_in[3];
  const float* scale_k = (const float*)d_in[4];
  float* out = (float*)d_out;

  // workspace (~44 MB)
  char* ws = (char*)d_ws;
  u16* qf = (u16*)(ws + 0);          // q f16 images [b*16+h][st][dhi][64r][32d]
  u16* kf = (u16*)(ws + 8388608);    // k (scaled) f16 images
  u16* Xp = (u16*)(ws + 16777216);   // X' f16 images [32][32][4096]
  u16* vT = (u16*)(ws + 25165824);   // v bf16 images [b*16+h][st][sh][64d][32s]
  u16* Wp = (u16*)(ws + 33554432);   // Wqkv'^T f16 images [24][32][4096]
  float* sums = (float*)(ws + 39845888);
  u16* Wop = (u16*)(ws + 41943040);  // Wo'^T images — dedicated slot
  u16* zp = Xp;                      // alias: X' dead after gemm_qkv

  // 4 dispatches: prep fuses conv_x + conv_w x2 + sums=0 (R9: −5.2 µs).
  prep_kernel<<<2560, 256, 0, stream>>>(x, Wqkv, Wo, Xp, Wp, Wop, sums);
  gemm_qkv_kernel<<<192, 512, 0, stream>>>(Xp, Wp, qf, kf, vT,
                                           scale_q, scale_k, sums);
  attn_kernel<<<512, 256, 0, stream>>>(qf, kf, vT, sums, zp);
  gemm_o_kernel<<<256, 256, 0, stream>>>(Wop, zp, out);
}

// Round 11
// 176.562 us; speedup vs baseline: 1.0316x; 1.0316x over previous
//
#include <hip/hip_runtime.h>

typedef float f32x4 __attribute__((ext_vector_type(4)));
typedef short bf16x8 __attribute__((ext_vector_type(8)));
typedef _Float16 f16x8 __attribute__((ext_vector_type(8)));
typedef unsigned short u16;

__device__ __forceinline__ u16 f2bf(float f) {
  unsigned int u = __float_as_uint(f);
  u = u + 0x7fffu + ((u >> 16) & 1u);  // RNE
  return (u16)(u >> 16);
}
__device__ __forceinline__ float bf2f(u16 h) {
  return __uint_as_float(((unsigned int)h) << 16);
}
__device__ __forceinline__ u16 f2h(float f) {
  _Float16 h = (_Float16)f;  // v_cvt_f16_f32, RNE
  union { _Float16 h; u16 u; } cv;
  cv.h = h;
  return cv.u;
}

typedef unsigned int as1_uint __attribute__((address_space(1)));
typedef unsigned int as3_uint __attribute__((address_space(3)));
// async global->LDS, 16B/lane; LDS dest = wave-uniform base + lane*16
__device__ __forceinline__ void gl_lds16(const void* g, void* l) {
  __builtin_amdgcn_global_load_lds((as1_uint*)g, (as3_uint*)l, 16, 0, 0);
}

// Image unit = 8KB: [128 rows][32 k] elems, chunk swizzle c' = c ^ ((r>>1)&3).
// Frag read offset in image: r*32 + ((quad ^ ((lm>>1)&3))*8) — 0-conflict.

// ============ fused prep: conv_x + conv_w(Wqkv) + conv_w(Wo) + sums=0 ======
// One dispatch replaces 3 kernels + 1 memset (verified R9: −5.2 µs).
__device__ __forceinline__ void conv_w_body(const float* __restrict__ src,
                                            int ncols, u16* __restrict__ dst,
                                            int slab, int kg,
                                            float (*tl)[132]) {
  const int t = threadIdx.x;
  const int n0 = slab * 128, k0 = kg * 64;
#pragma unroll
  for (int i = 0; i < 8; i++) {
    const int fidx = i * 256 + t;
    const int r = fidx >> 5, c4 = (fidx & 31) * 4;
    *(float4*)&tl[r][c4] = *(const float4*)&src[(size_t)(k0 + r) * ncols + n0 + c4];
  }
  __syncthreads();
  const size_t base = (size_t)slab * 131072 + (size_t)(kg * 2) * 4096;
#pragma unroll
  for (int i = 0; i < 4; i++) {
    const int g = i * 256 + t;
    const int img = g >> 9, ci = g & 511;
    const int r = ci >> 2, cp = ci & 3;
    const int c = cp ^ ((r >> 1) & 3);
    const int klc = img * 32 + c * 8;
    ushort4 h0, h1;
    float v[8];
#pragma unroll
    for (int e = 0; e < 8; e++) v[e] = tl[klc + e][r];
    h0.x = f2h(v[0]); h0.y = f2h(v[1]); h0.z = f2h(v[2]); h0.w = f2h(v[3]);
    h1.x = f2h(v[4]); h1.y = f2h(v[5]); h1.z = f2h(v[6]); h1.w = f2h(v[7]);
    *(ushort4*)&dst[base + g * 8] = h0;
    *(ushort4*)&dst[base + g * 8 + 4] = h1;
  }
}

__global__ __launch_bounds__(256) void prep_kernel(
    const float* __restrict__ x, const float* __restrict__ Wqkv,
    const float* __restrict__ Wo, u16* __restrict__ Xp, u16* __restrict__ Wp,
    u16* __restrict__ Wop, float* __restrict__ sums) {
  __shared__ float tl[64][132];
  const int L = blockIdx.x;
  if (L == 0 && threadIdx.x < 2) sums[threadIdx.x] = 0.f;
  if (L < 2048) {
    // conv_x: x f32 -> X' f16 images (32 slabs x 32 ksteps)
    const int g = L * 256 + threadIdx.x;
    const int o = g * 8;
    const int slab = o >> 17;
    const int rem = o & 131071;
    const int kstep = rem >> 12;
    const int rem2 = rem & 4095;
    const int r = rem2 >> 5;
    const int cp = (rem2 & 31) >> 3;
    const int c = cp ^ ((r >> 1) & 3);
    const int s = slab * 128 + r;
    const int k = kstep * 32 + c * 8;
    const float4 v0 = *(const float4*)&x[(size_t)s * 1024 + k];
    const float4 v1 = *(const float4*)&x[(size_t)s * 1024 + k + 4];
    ushort4 a, b;
    a.x = f2h(v0.x); a.y = f2h(v0.y); a.z = f2h(v0.z); a.w = f2h(v0.w);
    b.x = f2h(v1.x); b.y = f2h(v1.y); b.z = f2h(v1.z); b.w = f2h(v1.w);
    *(ushort4*)&Xp[o] = a;
    *(ushort4*)&Xp[o + 4] = b;
  } else if (L < 2432) {
    const int idx = L - 2048;  // 24 slabs x 16 kg
    conv_w_body(Wqkv, 3072, Wp, idx % 24, idx / 24, tl);
  } else {
    const int idx = L - 2432;  // 8 slabs x 16 kg
    conv_w_body(Wo, 1024, Wop, idx % 8, idx / 8, tl);
  }
}

// ======= fused qkv GEMM — 256x256 tile, 8 waves, BK=64, m201 phase order ===
// At structural ceiling: 594 TF at 75% grid fill = 792 TF/active-CU ≈ m248's
// 848 TF reference for 256²/8ph/K=1024. Frozen (verified R6).
__global__ __launch_bounds__(512, 2) void gemm_qkv_kernel(
    const u16* __restrict__ Xp, const u16* __restrict__ Wp,
    u16* __restrict__ qf, u16* __restrict__ kf, u16* __restrict__ vT,
    const float* __restrict__ scale_q, const float* __restrict__ scale_k,
    float* __restrict__ sums) {
  __shared__ u16 SA[2][4][4096];  // X-data: [buf][k2*2+slab][8KB image]
  __shared__ u16 SB[2][4][4096];  // W-data
  const int tid = threadIdx.x, wv = tid >> 6, lane = tid & 63;
  const int lm = lane & 15, quad = lane >> 4;
  const int wvM = wv >> 2, wvN = wv & 3;  // wave grid 2(M) x 4(N)
  // bijective XCD decode: 192 blocks = 8 xcd x 24; each xcd: 4 bm x 6 bn
  const int L = blockIdx.x;
  const int xcd = L & 7, idx = L >> 3;        // idx in [0,24)
  const int bmT = (xcd & 3) * 4 + (idx & 3);  // [0,16)
  const int bnT = (xcd >> 2) * 6 + (idx >> 2);// [0,12)
  const bool is_v = (bnT >= 8);
  const int fq = (quad ^ ((lm >> 1) & 3)) * 8;
  const int aOff = lm * 32 + fq;
  const u16* Xg = Xp + (size_t)bmT * 262144;  // 2 slabs of 128 rows
  const u16* Wg = Wp + (size_t)bnT * 262144;
  // B-frag sub/row bases for the 4 n-frags (B-row = wvN*64 + n*16 + lm)
  int bSub[4];
#pragma unroll
  for (int n = 0; n < 4; n++) {
    const int wn = wvN * 64 + n * 16;
    bSub[n] = ((wn >> 7) * 4096) + (wn & 127) * 32;
  }
  const u16* Ard = is_v ? &SA[0][0][0] : &SB[0][0][0];
  const u16* Brd = is_v ? &SB[0][0][0] : &SA[0][0][0];

  const f32x4 z4 = {0.f, 0.f, 0.f, 0.f};
  f32x4 acc[8][4];
#pragma unroll
  for (int i = 0; i < 8; i++)
#pragma unroll
    for (int j = 0; j < 4; j++) acc[i][j] = z4;

#define VMCNT4() asm volatile("s_waitcnt vmcnt(4)" ::: "memory")
#define VMCNT0() asm volatile("s_waitcnt vmcnt(0)" ::: "memory")
#define LGKM0() asm volatile("s_waitcnt lgkmcnt(0)" ::: "memory")
#define CFENCE() asm volatile("" ::: "memory")
#define SP1() __builtin_amdgcn_s_setprio(1)
#define SP0() __builtin_amdgcn_s_setprio(0)

  // stage one (X,W) sub-image pair (8KB each, 8 waves x 1KB) for tile tt
#define QSTAGE(tt, nb, k2, sl)                                               \
  do {                                                                       \
    const size_t go_ = (size_t)(sl)*131072 + (size_t)(2 * (tt) + (k2)) * 4096\
                       + wv * 512 + lane * 8;                                \
    gl_lds16(Xg + go_, &SA[nb][(k2)*2 + (sl)][wv * 512]);                    \
    gl_lds16(Wg + go_, &SB[nb][(k2)*2 + (sl)][wv * 512]);                    \
  } while (0)

#define READ_A(BUF, k2, mq)                                                  \
  _Pragma("unroll")                                                          \
  for (int i = 0; i < 4; i++)                                                \
    afr[i] = *(const f16x8*)&Ard[(BUF)*16384 + ((k2)*2 + wvM) * 4096 +       \
                                 ((mq)*4 + i) * 512 + aOff];
#define READ_B(BUF, k2)                                                      \
  _Pragma("unroll")                                                          \
  for (int n = 0; n < 4; n++)                                                \
    bfr[n] = *(const f16x8*)&Brd[(BUF)*16384 + (k2)*8192 + bSub[n] + aOff];
#define MFMA16(mq)                                                           \
  _Pragma("unroll")                                                          \
  for (int i = 0; i < 4; i++)                                                \
    _Pragma("unroll")                                                        \
    for (int n = 0; n < 4; n++)                                              \
      acc[(mq)*4 + i][n] = __builtin_amdgcn_mfma_f32_16x16x32_f16(           \
          afr[i], bfr[n], acc[(mq)*4 + i][n], 0, 0, 0);

#define PH_WAIT_MFMA(mq)                                                     \
  CFENCE();                                                                  \
  __builtin_amdgcn_s_barrier();                                              \
  CFENCE();                                                                  \
  LGKM0();                                                                   \
  __builtin_amdgcn_sched_barrier(0);                                         \
  SP1();                                                                     \
  MFMA16(mq);                                                                \
  SP0()

  // compute tile t from BUF; stage tile t+1 into NBUF (if DOSTAGE)
#define KTILE(BUF, NBUF, t, DOSTAGE, GATE1, GATE3)                           \
  do {                                                                       \
    f16x8 bfr[4];                                                            \
    { /* ph0: k2=0, m-low */                                                 \
      f16x8 afr[4];                                                          \
      READ_A(BUF, 0, 0);                                                     \
      READ_B(BUF, 0);                                                        \
      if (DOSTAGE) QSTAGE((t) + 1, NBUF, 0, 0);                              \
      PH_WAIT_MFMA(0);                                                       \
    }                                                                        \
    { /* ph1: k2=0, m-high */                                                \
      f16x8 afr[4];                                                          \
      READ_A(BUF, 0, 1);                                                     \
      if (DOSTAGE) QSTAGE((t) + 1, NBUF, 0, 1);                              \
      GATE1; /* drain oldest-4 = this tile's k2=1 half, read in ph2 */       \
      PH_WAIT_MFMA(1);                                                       \
    }                                                                        \
    { /* ph2: k2=1, m-low */                                                 \
      f16x8 afr[4];                                                          \
      READ_A(BUF, 1, 0);                                                     \
      READ_B(BUF, 1);                                                        \
      if (DOSTAGE) QSTAGE((t) + 1, NBUF, 1, 0);                              \
      PH_WAIT_MFMA(0);                                                       \
    }                                                                        \
    { /* ph3: k2=1, m-high */                                                \
      f16x8 afr[4];                                                          \
      READ_A(BUF, 1, 1);                                                     \
      if (DOSTAGE) QSTAGE((t) + 1, NBUF, 1, 1);                              \
      GATE3; /* drain oldest-4 = next tile's k2=0 half, read in next ph0 */  \
      PH_WAIT_MFMA(1);                                                       \
    }                                                                        \
    /* barrier_B (tile boundary): all waves consumed BUF before any wave   */\
    /* may issue next tile's re-stage into BUF.                            */\
    CFENCE();                                                                \
    __builtin_amdgcn_s_barrier();                                            \
    CFENCE();                                                                \
  } while (0)

  // prologue: stage tile 0 into buf0, k-major order; gate k2=0 + barrier
  QSTAGE(0, 0, 0, 0);
  QSTAGE(0, 0, 0, 1);
  QSTAGE(0, 0, 1, 0);
  QSTAGE(0, 0, 1, 1);
  VMCNT4();
  __builtin_amdgcn_s_barrier();
  CFENCE();
#pragma unroll 1
  for (int t = 0; t < 14; t += 2) {
    KTILE(0, 1, t, true, VMCNT4(), VMCNT4());
    KTILE(1, 0, t + 1, true, VMCNT4(), VMCNT4());
  }
  KTILE(0, 1, 14, true, VMCNT4(), VMCNT4());
  KTILE(1, 0, 15, false, VMCNT0(), (void)0);
#undef KTILE
#undef PH_WAIT_MFMA
#undef READ_A
#undef READ_B
#undef MFMA16
#undef QSTAGE

  const int bn = bnT * 256, bm = bmT * 256;
  if (!is_v) {
    // swapped: acc[mi][ni][i] = C[col=bn+wvM*128+mi*16+quad*4+i][s=...]
    const bool is_k = (bnT >= 4);
    u16* dst = is_k ? kf : qf;
    float ss = 0.f;
#pragma unroll
    for (int mi = 0; mi < 8; mi++) {
      const int col0 = bn + wvM * 128 + mi * 16 + quad * 4;
      const int hh = (col0 >> 6) & 15, d0 = col0 & 63;
      const int dhi = d0 >> 5, cc = (d0 & 31) >> 3, eo = d0 & 7;
      float sc[4] = {1.f, 1.f, 1.f, 1.f};
      if (is_k) {
        const float4 sq = *(const float4*)&scale_q[d0];
        const float4 sk = *(const float4*)&scale_k[d0];
        sc[0] = sq.x * sk.x; sc[1] = sq.y * sk.y;
        sc[2] = sq.z * sk.z; sc[3] = sq.w * sk.w;
      }
#pragma unroll
      for (int ni = 0; ni < 4; ni++) {
        const int s = bm + wvN * 64 + ni * 16 + lm;
        const int b = s >> 10, sl = s & 1023, st = sl >> 6, r = sl & 63;
        const size_t off = ((size_t)((b * 16 + hh) * 16 + st)) * 4096 +
                           dhi * 2048 + r * 32 + ((cc ^ ((r >> 1) & 3)) * 8) + eo;
        ushort4 h4;
#pragma unroll
        for (int i = 0; i < 4; i++) {
          const float a = acc[mi][ni][i];
          ss += a * a;  // raw (pre-scale) for global RMS
          const u16 hv = f2h(a * sc[i]);
          if (i == 0) h4.x = hv;
          else if (i == 1) h4.y = hv;
          else if (i == 2) h4.z = hv;
          else h4.w = hv;
        }
        *(ushort4*)&dst[off] = h4;
      }
    }
#pragma unroll
    for (int m = 32; m >= 1; m >>= 1) ss += __shfl_xor(ss, m, 64);
    if (lane == 0) atomicAdd(&sums[is_k ? 1 : 0], ss);
  } else {
    // normal: acc[mi][ni][i] = C[s=bm+wvM*128+mi*16+quad*4+i][d-col]; bf16
#pragma unroll
    for (int ni = 0; ni < 4; ni++) {
      const int col = (bn - 2048) + wvN * 64 + ni * 16 + lm;
      const int d = col & 63, hh = col >> 6;
#pragma unroll
      for (int mi = 0; mi < 8; mi++) {
        const int s0 = bm + wvM * 128 + mi * 16 + quad * 4;
        const int b = s0 >> 10, sl = s0 & 1023, st = sl >> 6;
        const int sh = (sl & 63) >> 5, cc = (sl & 31) >> 3, eo = sl & 7;
        const size_t off = ((size_t)((b * 16 + hh) * 16 + st)) * 4096 +
                           sh * 2048 + d * 32 + ((cc ^ ((d >> 1) & 3)) * 8) + eo;
        ushort4 v4;
        v4.x = f2bf(acc[mi][ni][0]);
        v4.y = f2bf(acc[mi][ni][1]);
        v4.z = f2bf(acc[mi][ni][2]);
        v4.w = f2bf(acc[mi][ni][3]);
        *(ushort4*)&vT[off] = v4;
      }
    }
  }
#undef VMCNT4
#undef VMCNT0
#undef LGKM0
#undef CFENCE
#undef SP1
#undef SP0
}

// ============ fused attention — f16 QK (swapped), bf16 PV (verified R6) ====
// Best-measured attn family (R3/R6/R9 = 178.2 µs total). R10's per-nt
// setprio toggling + exp2-fold measured −2.2% (too-fine prio churn) —
// reverted to this exact version. Staged dbuf, grid 512, XCD swizzle:
// xcd owns 8 (b,h) pairs x all 8 q-tiles -> K/V 2MB/XCD, L2-resident.
__global__ __launch_bounds__(256) void attn_kernel(
    const u16* __restrict__ qf, const u16* __restrict__ kf,
    const u16* __restrict__ vT, const float* __restrict__ sums,
    u16* __restrict__ z) {
  __shared__ u16 Ks0[4096], Vs0[4096], Ks1[4096], Vs1[4096];  // 32 KB
  __shared__ u16 pb[4][2][16][64];                            // 16 KB
  const int tid = threadIdx.x, wv = tid >> 6, lane = tid & 63;
  const int lm = lane & 15, quad = lane >> 4;
  const int fq = (quad ^ ((lm >> 1) & 3)) * 8;
  const int L = blockIdx.x;
  const int xcd = L & 7, idx = L >> 3;   // idx in [0,64)
  const int qt8 = idx & 7, p = idx >> 3; // p in [0,8)
  const int pair = xcd * 8 + p;          // [0,64)
  const int hh = pair & 15, b = pair >> 4;
  const float inv_rq = 1.f / (sqrtf(sums[0] * (1.f / 4194304.f)) + 1e-6f);
  const float inv_rk = 1.f / (sqrtf(sums[1] * (1.f / 4194304.f)) + 1e-6f);
  const float cs = inv_rq * inv_rk;
  const size_t hb = ((size_t)(b * 16 + hh)) * 65536;
  const u16* Kg = kf + hb;
  const u16* Vg = vT + hb;
  const int dof = wv * 1024;

  // q frags (B-operand role): B[n=lm][k=d], rows = wave's q set
  f16x8 aF[2][2];
#pragma unroll
  for (int qs = 0; qs < 2; qs++) {
    const int soff = wv * 32 + qs * 16;
    const size_t qb = hb + (size_t)(qt8 * 2 + (soff >> 6)) * 4096 +
                      (size_t)((soff & 63) + lm) * 32 + fq;
    aF[qs][0] = *(const f16x8*)&qf[qb];
    aF[qs][1] = *(const f16x8*)&qf[qb + 2048];
  }
  const f32x4 zz = {0.f, 0.f, 0.f, 0.f};
  f32x4 zac[2][4];
#pragma unroll
  for (int qs = 0; qs < 2; qs++)
#pragma unroll
    for (int dt = 0; dt < 4; dt++) zac[qs][dt] = zz;
  float rs[2] = {0.f, 0.f};

#define AISSUE(it, Ks, Vs)                                    \
  do {                                                        \
    const size_t tb_ = (size_t)(it) * 4096;                   \
    gl_lds16(Kg + tb_ + dof + lane * 8, &Ks[dof]);            \
    gl_lds16(Kg + tb_ + dof + 512 + lane * 8, &Ks[dof + 512]);\
    gl_lds16(Vg + tb_ + dof + lane * 8, &Vs[dof]);            \
    gl_lds16(Vg + tb_ + dof + 512 + lane * 8, &Vs[dof + 512]);\
  } while (0)

#define ATTN_BODY(it, Ks, Vs, Kn, Vn, do_issue)                               \
  do {                                                                        \
    /* pre-read all frags of this tile */                                     \
    f16x8 kf0[4], kf1[4];                                                     \
    bf16x8 bv[2][4];                                                          \
_Pragma("unroll")                                                             \
    for (int nt = 0; nt < 4; nt++) {                                          \
      const int ro = (nt * 16 + lm) * 32 + fq;                                \
      kf0[nt] = *(const f16x8*)&Ks[ro];                                       \
      kf1[nt] = *(const f16x8*)&Ks[2048 + ro];                                \
    }                                                                         \
_Pragma("unroll")                                                             \
    for (int ch = 0; ch < 2; ch++)                                            \
_Pragma("unroll")                                                             \
      for (int dt = 0; dt < 4; dt++)                                          \
        bv[ch][dt] = *(const bf16x8*)&Vs[ch * 2048 + (dt * 16 + lm) * 32 + fq];\
    if (do_issue) AISSUE((it) + 1, Kn, Vn);                                   \
    /* QK swapped + softmax numerator + p to LDS (b64, swizzled) */           \
_Pragma("unroll")                                                             \
    for (int qs = 0; qs < 2; qs++) {                                          \
_Pragma("unroll")                                                             \
      for (int nt = 0; nt < 4; nt++) {                                        \
        f32x4 c = zz;                                                         \
        c = __builtin_amdgcn_mfma_f32_16x16x32_f16(kf0[nt], aF[qs][0], c, 0, 0, 0);\
        c = __builtin_amdgcn_mfma_f32_16x16x32_f16(kf1[nt], aF[qs][1], c, 0, 0, 0);\
        const int k4 = nt * 4 + quad;                                         \
        const int sw = (k4 & 8) | ((k4 ^ lm) & 7);                            \
        ushort4 pw;                                                           \
        float p0 = __expf(c[0] * cs - 60.f);                                  \
        float p1 = __expf(c[1] * cs - 60.f);                                  \
        float p2 = __expf(c[2] * cs - 60.f);                                  \
        float p3 = __expf(c[3] * cs - 60.f);                                  \
        rs[qs] += (p0 + p1) + (p2 + p3);                                      \
        pw.x = f2bf(p0); pw.y = f2bf(p1); pw.z = f2bf(p2); pw.w = f2bf(p3);   \
        *(ushort4*)&pb[wv][qs][lm][sw * 4] = pw;                              \
      }                                                                       \
    }                                                                         \
    /* PV swapped: A=v rows=d, B=p rows=q (b64 pair reads, swizzled) */       \
_Pragma("unroll")                                                             \
    for (int ch = 0; ch < 2; ch++) {                                          \
_Pragma("unroll")                                                             \
      for (int qs = 0; qs < 2; qs++) {                                        \
        const int k4a = ch * 8 + quad * 2, k4b = k4a + 1;                     \
        const ushort4 lo4 =                                                   \
            *(const ushort4*)&pb[wv][qs][lm][((k4a & 8) | ((k4a ^ lm) & 7)) * 4];\
        const ushort4 hi4 =                                                   \
            *(const ushort4*)&pb[wv][qs][lm][((k4b & 8) | ((k4b ^ lm) & 7)) * 4];\
        bf16x8 ap;                                                            \
        ap[0] = (short)lo4.x; ap[1] = (short)lo4.y;                           \
        ap[2] = (short)lo4.z; ap[3] = (short)lo4.w;                           \
        ap[4] = (short)hi4.x; ap[5] = (short)hi4.y;                           \
        ap[6] = (short)hi4.z; ap[7] = (short)hi4.w;                           \
_Pragma("unroll")                                                             \
        for (int dt = 0; dt < 4; dt++)                                        \
          zac[qs][dt] = __builtin_amdgcn_mfma_f32_16x16x32_bf16(              \
              bv[ch][dt], ap, zac[qs][dt], 0, 0, 0);                          \
      }                                                                       \
    }                                                                         \
  } while (0)

  AISSUE(0, Ks0, Vs0);
  for (int it = 0; it < 16; it += 2) {
    __syncthreads();
    ATTN_BODY(it, Ks0, Vs0, Ks1, Vs1, true);
    __syncthreads();
    ATTN_BODY(it + 1, Ks1, Vs1, Ks0, Vs0, (it + 2 < 16));
  }
#undef AISSUE
#undef ATTN_BODY

  // rowsum for q=lm: reduce over quad groups only
#pragma unroll
  for (int qs = 0; qs < 2; qs++) {
    rs[qs] += __shfl_xor(rs[qs], 16, 64);
    rs[qs] += __shfl_xor(rs[qs], 32, 64);
  }
  const int slab = b * 8 + qt8;
#pragma unroll
  for (int qs = 0; qs < 2; qs++) {
    const float inv = 1.f / rs[qs];
    const int r = wv * 32 + qs * 16 + lm;
#pragma unroll
    for (int dt = 0; dt < 4; dt++) {
      const int kstep = hh * 2 + (dt >> 1);
      const int d0 = dt * 16 + quad * 4;
      const int cc = (d0 & 31) >> 3, eo = d0 & 7;
      const size_t off = ((size_t)(slab * 32 + kstep)) * 4096 + r * 32 +
                         ((cc ^ ((r >> 1) & 3)) * 8) + eo;
      ushort4 o;
      o.x = f2h(zac[qs][dt][0] * inv);
      o.y = f2h(zac[qs][dt][1] * inv);
      o.z = f2h(zac[qs][dt][2] * inv);
      o.w = f2h(zac[qs][dt][3] * inv);
      *(ushort4*)&z[off] = o;
    }
  }
}

// ============ output projection — f16, async-LDS dbuf, swapped =============
// XCD swizzle: flat grid 256; xcd owns 8 zp-slabs x 4 Wo-slabs -> 3MB L2 set.
__global__ __launch_bounds__(256) void gemm_o_kernel(const u16* __restrict__ Wop,
                                                     const u16* __restrict__ zp,
                                                     float* __restrict__ out) {
  __shared__ u16 As0[4096], Bs0[4096], As1[4096], Bs1[4096];
  const int tid = threadIdx.x, wv = tid >> 6, lane = tid & 63;
  const int lm = lane & 15, quad = lane >> 4;
  const int wr = (wv >> 1) * 64, wc = (wv & 1) * 64;
  const int fq = (quad ^ ((lm >> 1) & 3)) * 8;
  const int L = blockIdx.x;
  const int xcd = L & 7, idx = L >> 3;      // idx in [0,32)
  const int rr = idx & 7, cc8 = idx >> 3;   // 8 zp x 4 Wo
  const int zpS = (xcd & 3) * 8 + rr;       // [0,32)
  const int woS = (xcd >> 2) * 4 + cc8;     // [0,8)
  const u16* Ag = Wop + (size_t)woS * 131072;
  const u16* Bg = zp + (size_t)zpS * 131072;
  const int dof0 = (wv * 2) * 512, dof1 = (wv * 2 + 1) * 512;
  const f32x4 z4 = {0.f, 0.f, 0.f, 0.f};
  f32x4 acc[4][4];
#pragma unroll
  for (int i = 0; i < 4; i++)
#pragma unroll
    for (int j = 0; j < 4; j++) acc[i][j] = z4;

#define ISSUE(t, As, Bs)                                   \
  do {                                                     \
    const size_t tb_ = (size_t)(t) * 4096;                 \
    gl_lds16(Ag + tb_ + dof0 + lane * 8, &As[dof0]);       \
    gl_lds16(Ag + tb_ + dof1 + lane * 8, &As[dof1]);       \
    gl_lds16(Bg + tb_ + dof0 + lane * 8, &Bs[dof0]);       \
    gl_lds16(Bg + tb_ + dof1 + lane * 8, &Bs[dof1]);       \
  } while (0)
#define GBODY(As, Bs)                                                     \
  do {                                                                    \
    f16x8 afr[4], bfr[4];                                                 \
_Pragma("unroll")                                                         \
    for (int mi = 0; mi < 4; mi++)                                        \
      afr[mi] = *(const f16x8*)&As[(wr + mi * 16 + lm) * 32 + fq];        \
_Pragma("unroll")                                                         \
    for (int ni = 0; ni < 4; ni++)                                        \
      bfr[ni] = *(const f16x8*)&Bs[(wc + ni * 16 + lm) * 32 + fq];        \
    DO_ISSUE;                                                             \
_Pragma("unroll")                                                         \
    for (int mi = 0; mi < 4; mi++)                                        \
_Pragma("unroll")                                                         \
      for (int ni = 0; ni < 4; ni++)                                      \
        acc[mi][ni] = __builtin_amdgcn_mfma_f32_16x16x32_f16(             \
            afr[mi], bfr[ni], acc[mi][ni], 0, 0, 0);                      \
  } while (0)

  ISSUE(0, As0, Bs0);
  for (int t = 0; t < 32; t += 2) {
    __syncthreads();
#define DO_ISSUE ISSUE(t + 1, As1, Bs1)
    GBODY(As0, Bs0);
#undef DO_ISSUE
    __syncthreads();
#define DO_ISSUE if (t + 2 < 32) ISSUE(t + 2, As0, Bs0)
    GBODY(As1, Bs1);
#undef DO_ISSUE
  }
#undef ISSUE
#undef GBODY

#pragma unroll
  for (int mi = 0; mi < 4; mi++) {
    const int col0 = woS * 128 + wr + mi * 16 + quad * 4;
#pragma unroll
    for (int ni = 0; ni < 4; ni++) {
      const int s = zpS * 128 + wc + ni * 16 + lm;
      const float4 o = {acc[mi][ni][0], acc[mi][ni][1], acc[mi][ni][2],
                        acc[mi][ni][3]};
      *(float4*)&out[(size_t)s * 1024 + col0] = o;
    }
  }
}

extern "C" void kernel_launch(void* const* d_in, const int* in_sizes, int n_in,
                              void* d_out, int out_size, void* d_ws,
                              size_t ws_size, hipStream_t stream) {
  (void)in_sizes; (void)n_in; (void)out_size; (void)ws_size;
  const float* x = (const float*)d_in[0];
  const float* Wqkv = (const float*)d_in[1];
  const float* Wo = (const float*)d_in[2];
  const float* scale_q = (const float*)d_in[3];
  const float* scale_k = (const float*)d_in[4];
  float* out = (float*)d_out;

  // workspace (~44 MB)
  char* ws = (char*)d_ws;
  u16* qf = (u16*)(ws + 0);          // q f16 images [b*16+h][st][dhi][64r][32d]
  u16* kf = (u16*)(ws + 8388608);    // k (scaled) f16 images
  u16* Xp = (u16*)(ws + 16777216);   // X' f16 images [32][32][4096]
  u16* vT = (u16*)(ws + 25165824);   // v bf16 images [b*16+h][st][sh][64d][32s]
  u16* Wp = (u16*)(ws + 33554432);   // Wqkv'^T f16 images [24][32][4096]
  float* sums = (float*)(ws + 39845888);
  u16* Wop = (u16*)(ws + 41943040);  // Wo'^T images — dedicated slot
  u16* zp = Xp;                      // alias: X' dead after gemm_qkv

  // 4 dispatches: prep fuses conv_x + conv_w x2 + sums=0 (R9: −5.2 µs).
  prep_kernel<<<2560, 256, 0, stream>>>(x, Wqkv, Wo, Xp, Wp, Wop, sums);
  gemm_qkv_kernel<<<192, 512, 0, stream>>>(Xp, Wp, qf, kf, vT,
                                           scale_q, scale_k, sums);
  attn_kernel<<<512, 256, 0, stream>>>(qf, kf, vT, sums, zp);
  gemm_o_kernel<<<256, 256, 0, stream>>>(Wop, zp, out);
}